// Round 12
// baseline (582.424 us; speedup 1.0000x reference)
//
#include <hip/hip_runtime.h>

#define NN 512
#define BATCH 256
#define T 8

typedef unsigned long long u64;
typedef unsigned u32;
typedef unsigned char u8;

// u64 max/min via f64: all keys are positive f64 bit patterns (< 2^62,
// exponent never all-ones) -> IEEE order == unsigned order. 1 instr each.
__device__ __forceinline__ u64 fm(u64 a, u64 b) {
    return (u64)__double_as_longlong(fmax(__longlong_as_double((long long)a),
                                          __longlong_as_double((long long)b)));
}
__device__ __forceinline__ u64 fmn(u64 a, u64 b) {
    return (u64)__double_as_longlong(fmin(__longlong_as_double((long long)a),
                                          __longlong_as_double((long long)b)));
}

#define DPP_FMAX64(k, ctrl) do {                                              \
    int _lo = (int)(u32)(k); int _hi = (int)((k) >> 32);                      \
    int _olo = __builtin_amdgcn_update_dpp(_lo, _lo, ctrl, 0xf, 0xf, false);  \
    int _ohi = __builtin_amdgcn_update_dpp(_hi, _hi, ctrl, 0xf, 0xf, false);  \
    u64 _o = ((u64)(u32)_ohi << 32) | (u32)_olo;                              \
    (k) = fm((k), _o);                                                        \
} while (0)

#define WAVE_FMAX64(k) do {                                                   \
    DPP_FMAX64(k, 0x111); DPP_FMAX64(k, 0x112); DPP_FMAX64(k, 0x114);         \
    DPP_FMAX64(k, 0x118); DPP_FMAX64(k, 0x142); DPP_FMAX64(k, 0x143);         \
} while (0)

// sorted-desc top-8 insertion chain (t0 >= t1 >= ... >= t7)
#define INS8(X, A0, A1, A2, A3, A4, A5, A6, A7) do {                          \
    u64 _x = (X), _n;                                                         \
    _n = fm(A0, _x); _x = fmn(A0, _x); A0 = _n;                               \
    _n = fm(A1, _x); _x = fmn(A1, _x); A1 = _n;                               \
    _n = fm(A2, _x); _x = fmn(A2, _x); A2 = _n;                               \
    _n = fm(A3, _x); _x = fmn(A3, _x); A3 = _n;                               \
    _n = fm(A4, _x); _x = fmn(A4, _x); A4 = _n;                               \
    _n = fm(A5, _x); _x = fmn(A5, _x); A5 = _n;                               \
    _n = fm(A6, _x); _x = fmn(A6, _x); A6 = _n;                               \
    A7 = fm(A7, _x);                                                          \
} while (0)

__device__ __forceinline__ u32 cntlt(u64 m) {
    return __builtin_amdgcn_mbcnt_hi((u32)(m >> 32),
                                     __builtin_amdgcn_mbcnt_lo((u32)m, 0));
}

// ---------------------------------------------------------------------------
// Kernel 1: per-ROW top-T (desc val, asc col) -> out[b] bytes [0, 32K).
// Entry: val_bits<<32 | col.  (proven across rounds 2-10)
// ---------------------------------------------------------------------------
__global__ __launch_bounds__(256) void build_top(const float* __restrict__ s,
                                                 float* __restrict__ out) {
    const int wave = threadIdx.x >> 6;
    const int lane = threadIdx.x & 63;
    const int row_g = blockIdx.x * 4 + wave;
    const int b = row_g >> 9;
    const int r = row_g & (NN - 1);
    const float* rp = s + (size_t)row_g * NN;
    u64* dst = (u64*)(out + (size_t)b * NN * NN) + (size_t)r * T;

    const float4 a  = *(const float4*)(rp + 4 * lane);
    const float4 c2 = *(const float4*)(rp + 256 + 4 * lane);

    u64 kk0 = (((u64)__float_as_uint(a.x)  + 1) << 9) | (u32)(511 - (4*lane + 0));
    u64 kk1 = (((u64)__float_as_uint(a.y)  + 1) << 9) | (u32)(511 - (4*lane + 1));
    u64 kk2 = (((u64)__float_as_uint(a.z)  + 1) << 9) | (u32)(511 - (4*lane + 2));
    u64 kk3 = (((u64)__float_as_uint(a.w)  + 1) << 9) | (u32)(511 - (4*lane + 3));
    u64 kk4 = (((u64)__float_as_uint(c2.x) + 1) << 9) | (u32)(511 - (256 + 4*lane + 0));
    u64 kk5 = (((u64)__float_as_uint(c2.y) + 1) << 9) | (u32)(511 - (256 + 4*lane + 1));
    u64 kk6 = (((u64)__float_as_uint(c2.z) + 1) << 9) | (u32)(511 - (256 + 4*lane + 2));
    u64 kk7 = (((u64)__float_as_uint(c2.w) + 1) << 9) | (u32)(511 - (256 + 4*lane + 3));

    #pragma unroll
    for (int t = 0; t < T; ++t) {
        u64 m0 = fm(kk0, kk1), m1 = fm(kk2, kk3);
        u64 m2 = fm(kk4, kk5), m3 = fm(kk6, kk7);
        m0 = fm(m0, m1); m2 = fm(m2, m3);
        u64 bk = fm(m0, m2);
        WAVE_FMAX64(bk);
        const u32 blo = (u32)__builtin_amdgcn_readlane((int)(u32)bk, 63);
        const u32 bhi = (u32)__builtin_amdgcn_readlane((int)(bk >> 32), 63);
        const u64 bku = ((u64)bhi << 32) | blo;

        const int wcol = 511 - (int)(bku & 511);
        const u32 vb = (u32)(bku >> 9) - 1u;
        if (lane == 0) dst[t] = ((u64)vb << 32) | (u32)wcol;

        const int owner = (wcol & 255) >> 2;
        const int slot  = ((wcol >> 8) << 2) | (wcol & 3);
        if (lane == owner) {
            kk0 = (slot == 0) ? 0 : kk0;  kk1 = (slot == 1) ? 0 : kk1;
            kk2 = (slot == 2) ? 0 : kk2;  kk3 = (slot == 3) ? 0 : kk3;
            kk4 = (slot == 4) ? 0 : kk4;  kk5 = (slot == 5) ? 0 : kk5;
            kk6 = (slot == 6) ? 0 : kk6;  kk7 = (slot == 7) ? 0 : kk7;
        }
    }
}

// ---------------------------------------------------------------------------
// Kernel 1b: per-COL top-T (desc val, asc row) -> out[b] bytes [32K, 64K).
// Entry: tie-key ((val_bits+1)<<9) | (511-row)  (decode: row = 511-(k&511)).
// Block = (batch, 64-col strip); 64x64 tiles staged via LDS for coalescing.
// ---------------------------------------------------------------------------
__global__ __launch_bounds__(256) void build_col(const float* __restrict__ s,
                                                 float* __restrict__ out) {
    const int b = blockIdx.x >> 3;
    const int cbase = (blockIdx.x & 7) * 64;
    const int t = threadIdx.x;
    const int ct = t & 63, q = t >> 6;

    __shared__ float tile[64][65];
    __shared__ u64 mrg[64][4][8];

    const float* sb = s + (size_t)b * NN * NN;

    u64 t0 = 0, t1 = 0, t2 = 0, t3 = 0, t4 = 0, t5 = 0, t6 = 0, t7 = 0;

    for (int ch = 0; ch < 8; ++ch) {
        const int rbase = ch * 64;
        #pragma unroll
        for (int i = 0; i < 16; ++i) {
            const int rl_ = q + 4 * i;
            tile[rl_][ct] = sb[(size_t)(rbase + rl_) * NN + cbase + ct];
        }
        __syncthreads();
        #pragma unroll
        for (int i = 0; i < 16; ++i) {
            const int rr = rbase + q * 16 + i;
            const float v = tile[q * 16 + i][ct];
            const u64 x = (((u64)__float_as_uint(v) + 1) << 9) | (u32)(511 - rr);
            INS8(x, t0, t1, t2, t3, t4, t5, t6, t7);
        }
        __syncthreads();
    }

    mrg[ct][q][0] = t0;  mrg[ct][q][1] = t1;  mrg[ct][q][2] = t2;
    mrg[ct][q][3] = t3;  mrg[ct][q][4] = t4;  mrg[ct][q][5] = t5;
    mrg[ct][q][6] = t6;  mrg[ct][q][7] = t7;
    __syncthreads();

    if (t < 64) {
        u64 m0 = 0, m1 = 0, m2 = 0, m3 = 0, m4 = 0, m5 = 0, m6 = 0, m7 = 0;
        #pragma unroll
        for (int qq = 0; qq < 4; ++qq)
            #pragma unroll
            for (int ii = 0; ii < 8; ++ii) {
                const u64 x = mrg[t][qq][ii];
                INS8(x, m0, m1, m2, m3, m4, m5, m6, m7);
            }
        u64* dst = (u64*)(out + (size_t)b * NN * NN) + (size_t)NN * T
                 + (size_t)(cbase + t) * T;
        dst[0] = m0; dst[1] = m1; dst[2] = m2; dst[3] = m3;
        dst[4] = m4; dst[5] = m5; dst[6] = m6; dst[7] = m7;
    }
}

// ---------------------------------------------------------------------------
// Kernel 2: EXACT PARALLEL GREEDY via locally-dominant handshake.
// Round: (P1) commit all (r,c) with rowhead[r]==c AND colhead[c]==r;
// (P2) apply commits (output rows, kill rows/cols); (P3/P4) repair row/col
// heads via sorted LDS lists + alive bytes; rare cold reloads from HBM.
// Theorem: with the unique total order (val desc, row asc, col asc) this
// produces exactly the sequential flat-argmax greedy matching.
// ---------------------------------------------------------------------------
__global__ __launch_bounds__(64) void greedy_ps(const float* __restrict__ s,
                                                float* __restrict__ out) {
    __shared__ __align__(16) u64 rl[NN][T];    // 32 KB row lists
    __shared__ __align__(16) u64 cl[NN][T];    // 32 KB col lists
    __shared__ u32 colh[NN];                   // 2 KB: col -> head row
    __shared__ __align__(4) u8 aliveR[NN];
    __shared__ __align__(4) u8 aliveC[NN];
    __shared__ u32 cm[NN];                     // commit list (r<<16|c)

    const int b = blockIdx.x;
    const int lane = threadIdx.x;
    const float* sb = s + (size_t)b * NN * NN;
    float* ob = out + (size_t)b * NN * NN;

    // ---- stage lists ----
    {
        const ulonglong2* src = (const ulonglong2*)ob;
        ulonglong2* dR = (ulonglong2*)&rl[0][0];
        ulonglong2* dC = (ulonglong2*)&cl[0][0];
        #pragma unroll
        for (int j = 0; j < 32; ++j) {
            dR[lane + 64 * j] = src[lane + 64 * j];
            dC[lane + 64 * j] = src[2048 + lane + 64 * j];
        }
    }
    ((u32*)aliveR)[lane] = 0x01010101u;  ((u32*)aliveR)[64 + lane] = 0x01010101u;
    ((u32*)aliveC)[lane] = 0x01010101u;  ((u32*)aliveC)[64 + lane] = 0x01010101u;

    u32 rowhC[8], colhR[8];
    u32 rptr = 0, cptr = 0;
    u32 aliveRloc = 0xFFu, aliveCloc = 0xFFu;
    #pragma unroll
    for (int j = 0; j < 8; ++j) {
        const int r = lane + 64 * j;
        rowhC[j] = (u32)rl[r][0] & 511u;
        colhR[j] = 511u - ((u32)cl[r][0] & 511u);
        colh[r] = colhR[j];
    }

    const float4 z4 = {0.0f, 0.0f, 0.0f, 0.0f};
    int done = 0;

    for (int round = 0; round < 4096; ++round) {
        // ---- P1: handshake detect ----
        u32 m8 = 0;
        #pragma unroll
        for (int j = 0; j < 8; ++j) {
            const u32 c = rowhC[j];
            const bool hit = ((aliveRloc >> j) & 1u) &&
                             (colh[c] == (u32)(lane + 64 * j));
            m8 |= hit ? (1u << j) : 0u;
        }
        int cnt = 0;
        #pragma unroll
        for (int j = 0; j < 8; ++j) {
            const bool f = (m8 >> j) & 1u;
            const u64 bj = __ballot(f);
            if (bj) {
                if (f) cm[cnt + cntlt(bj)] =
                        ((u32)(lane + 64 * j) << 16) | rowhC[j];
                cnt += (int)__builtin_popcountll(bj);
            }
        }
        if (cnt == 0) break;   // cannot happen (global max always handshakes)

        // ---- P2: apply commits ----
        for (int i = 0; i < cnt; ++i) {
            const u32 e = cm[i];
            const int r = (int)(e >> 16), c = (int)(e & 511u);
            float* orow = ob + ((size_t)r << 9);
            *(float4*)(orow + 4 * lane) = z4;
            *(float4*)(orow + 256 + 4 * lane) = z4;
            if (lane == ((c & 255) >> 2)) orow[c] = 1.0f;
            if (lane == (r & 63)) aliveRloc &= ~(1u << (r >> 6));
            if (lane == (c & 63)) aliveCloc &= ~(1u << (c >> 6));
            if (lane == 0) { aliveR[r] = 0; aliveC[c] = 0; }
        }
        done += cnt;
        if (done >= NN) break;

        // ---- P3: repair row heads ----
        u32 coldR = 0;
        #pragma unroll
        for (int j = 0; j < 8; ++j) {
            if ((aliveRloc >> j) & 1u) {
                const int r = lane + 64 * j;
                if (!aliveC[rowhC[j]]) {
                    int p = (int)((rptr >> (4 * j)) & 15u);
                    u32 nc = 0xFFFFu;
                    while (++p < 8) {
                        const u32 cc = (u32)rl[r][p] & 511u;
                        if (aliveC[cc]) { nc = cc; break; }
                    }
                    if (nc != 0xFFFFu) {
                        rowhC[j] = nc;
                        rptr = (rptr & ~(15u << (4 * j))) | ((u32)p << (4 * j));
                    } else {
                        coldR |= 1u << j;
                        rptr |= 15u << (4 * j);
                    }
                }
            }
        }
        // cold rows: cooperative full-row reload
        u64 mk = __ballot(coldR != 0u);
        while (mk) {
            const int l = (int)__builtin_ctzll(mk); mk &= mk - 1;
            u32 lm = (u32)__builtin_amdgcn_readlane((int)coldR, l);
            while (lm) {
                const int j = (int)__builtin_ctz(lm); lm &= lm - 1;
                const int r = l + 64 * j;
                const float* rp = sb + (size_t)r * NN;
                const float4 fa = *(const float4*)(rp + 4 * lane);
                const float4 fv = *(const float4*)(rp + 256 + 4 * lane);
                const u32 wA = ((const u32*)aliveC)[lane];
                const u32 wB = ((const u32*)aliveC)[64 + lane];
                u64 e0 = (wA & 0xFFu)       ? ((((u64)__float_as_uint(fa.x) + 1) << 9) | (u32)(511 - (4*lane+0))) : 0;
                u64 e1 = (wA & 0xFF00u)     ? ((((u64)__float_as_uint(fa.y) + 1) << 9) | (u32)(511 - (4*lane+1))) : 0;
                u64 e2 = (wA & 0xFF0000u)   ? ((((u64)__float_as_uint(fa.z) + 1) << 9) | (u32)(511 - (4*lane+2))) : 0;
                u64 e3 = (wA & 0xFF000000u) ? ((((u64)__float_as_uint(fa.w) + 1) << 9) | (u32)(511 - (4*lane+3))) : 0;
                u64 e4 = (wB & 0xFFu)       ? ((((u64)__float_as_uint(fv.x) + 1) << 9) | (u32)(511 - (256+4*lane+0))) : 0;
                u64 e5 = (wB & 0xFF00u)     ? ((((u64)__float_as_uint(fv.y) + 1) << 9) | (u32)(511 - (256+4*lane+1))) : 0;
                u64 e6 = (wB & 0xFF0000u)   ? ((((u64)__float_as_uint(fv.z) + 1) << 9) | (u32)(511 - (256+4*lane+2))) : 0;
                u64 e7 = (wB & 0xFF000000u) ? ((((u64)__float_as_uint(fv.w) + 1) << 9) | (u32)(511 - (256+4*lane+3))) : 0;
                u64 n0 = fm(e0, e1), n1 = fm(e2, e3);
                u64 n2 = fm(e4, e5), n3 = fm(e6, e7);
                n0 = fm(n0, n1); n2 = fm(n2, n3);
                u64 bw = fm(n0, n2);
                WAVE_FMAX64(bw);
                const u32 lo = (u32)__builtin_amdgcn_readlane((int)(u32)bw, 63);
                const u32 nc = 511u - (lo & 511u);
                const bool mine = (lane == l);
                rowhC[0] = (mine && j == 0) ? nc : rowhC[0];
                rowhC[1] = (mine && j == 1) ? nc : rowhC[1];
                rowhC[2] = (mine && j == 2) ? nc : rowhC[2];
                rowhC[3] = (mine && j == 3) ? nc : rowhC[3];
                rowhC[4] = (mine && j == 4) ? nc : rowhC[4];
                rowhC[5] = (mine && j == 5) ? nc : rowhC[5];
                rowhC[6] = (mine && j == 6) ? nc : rowhC[6];
                rowhC[7] = (mine && j == 7) ? nc : rowhC[7];
            }
        }

        // ---- P4: repair col heads ----
        u32 coldC = 0;
        #pragma unroll
        for (int j = 0; j < 8; ++j) {
            if ((aliveCloc >> j) & 1u) {
                const int c = lane + 64 * j;
                if (!aliveR[colhR[j]]) {
                    int p = (int)((cptr >> (4 * j)) & 15u);
                    u32 nr = 0xFFFFu;
                    while (++p < 8) {
                        const u32 r2 = 511u - ((u32)cl[c][p] & 511u);
                        if (aliveR[r2]) { nr = r2; break; }
                    }
                    if (nr != 0xFFFFu) {
                        colhR[j] = nr;
                        colh[c] = nr;
                        cptr = (cptr & ~(15u << (4 * j))) | ((u32)p << (4 * j));
                    } else {
                        coldC |= 1u << j;
                        cptr |= 15u << (4 * j);
                    }
                }
            }
        }
        // cold cols: cooperative strided column reload
        mk = __ballot(coldC != 0u);
        while (mk) {
            const int l = (int)__builtin_ctzll(mk); mk &= mk - 1;
            u32 lm = (u32)__builtin_amdgcn_readlane((int)coldC, l);
            while (lm) {
                const int j = (int)__builtin_ctz(lm); lm &= lm - 1;
                const int c = l + 64 * j;
                u64 e[8];
                #pragma unroll
                for (int i = 0; i < 8; ++i) {
                    const int rr = lane + 64 * i;
                    const float v = sb[(size_t)rr * NN + c];
                    e[i] = aliveR[rr]
                         ? ((((u64)__float_as_uint(v) + 1) << 9) | (u32)(511 - rr))
                         : 0;
                }
                u64 n0 = fm(e[0], e[1]), n1 = fm(e[2], e[3]);
                u64 n2 = fm(e[4], e[5]), n3 = fm(e[6], e[7]);
                n0 = fm(n0, n1); n2 = fm(n2, n3);
                u64 bw = fm(n0, n2);
                WAVE_FMAX64(bw);
                const u32 lo = (u32)__builtin_amdgcn_readlane((int)(u32)bw, 63);
                const u32 nr = 511u - (lo & 511u);
                const bool mine = (lane == l);
                colhR[0] = (mine && j == 0) ? nr : colhR[0];
                colhR[1] = (mine && j == 1) ? nr : colhR[1];
                colhR[2] = (mine && j == 2) ? nr : colhR[2];
                colhR[3] = (mine && j == 3) ? nr : colhR[3];
                colhR[4] = (mine && j == 4) ? nr : colhR[4];
                colhR[5] = (mine && j == 5) ? nr : colhR[5];
                colhR[6] = (mine && j == 6) ? nr : colhR[6];
                colhR[7] = (mine && j == 7) ? nr : colhR[7];
                if (lane == 0) colh[c] = nr;
            }
        }
    }
}

extern "C" void kernel_launch(void* const* d_in, const int* in_sizes, int n_in,
                              void* d_out, int out_size, void* d_ws, size_t ws_size,
                              hipStream_t stream) {
    const float* s = (const float*)d_in[0];
    float* out = (float*)d_out;

    build_top<<<dim3(BATCH * NN / 4), dim3(256), 0, stream>>>(s, out);
    build_col<<<dim3(BATCH * 8), dim3(256), 0, stream>>>(s, out);
    greedy_ps<<<dim3(BATCH), dim3(64), 0, stream>>>(s, out);
}

// Round 13
// 484.589 us; speedup vs baseline: 1.2019x; 1.2019x over previous
//
#include <hip/hip_runtime.h>

#define NN 512
#define BATCH 256
#define T 8
#define ATH 80

typedef unsigned long long u64;
typedef unsigned u32;
typedef unsigned char u8;
typedef unsigned short u16;

#define DEADK 512ull
#define LIVEMIN (1ull << 32)

// u64 max/min via f64: keys are positive f64 bit patterns (< 2^62) ->
// IEEE order == unsigned order. 1 instr each.
__device__ __forceinline__ u64 fm(u64 a, u64 b) {
    return (u64)__double_as_longlong(fmax(__longlong_as_double((long long)a),
                                          __longlong_as_double((long long)b)));
}
__device__ __forceinline__ u64 fmn(u64 a, u64 b) {
    return (u64)__double_as_longlong(fmin(__longlong_as_double((long long)a),
                                          __longlong_as_double((long long)b)));
}

#define DPP_FMAX64(k, ctrl) do {                                              \
    int _lo = (int)(u32)(k); int _hi = (int)((k) >> 32);                      \
    int _olo = __builtin_amdgcn_update_dpp(_lo, _lo, ctrl, 0xf, 0xf, false);  \
    int _ohi = __builtin_amdgcn_update_dpp(_hi, _hi, ctrl, 0xf, 0xf, false);  \
    u64 _o = ((u64)(u32)_ohi << 32) | (u32)_olo;                              \
    (k) = fm((k), _o);                                                        \
} while (0)

#define WAVE_FMAX64(k) do {                                                   \
    DPP_FMAX64(k, 0x111); DPP_FMAX64(k, 0x112); DPP_FMAX64(k, 0x114);         \
    DPP_FMAX64(k, 0x118); DPP_FMAX64(k, 0x142); DPP_FMAX64(k, 0x143);         \
} while (0)

__device__ __forceinline__ u64 readlane64(u64 k, int l) {
    u32 lo = (u32)__builtin_amdgcn_readlane((int)(u32)k, l);
    u32 hi = (u32)__builtin_amdgcn_readlane((int)(k >> 32), l);
    return ((u64)hi << 32) | lo;
}

__device__ __forceinline__ u64 amsel(int w, u64 a0, u64 a1, u64 a2, u64 a3,
                                     u64 a4, u64 a5, u64 a6, u64 a7) {
    u64 x01 = (w & 1) ? a1 : a0;
    u64 x23 = (w & 1) ? a3 : a2;
    u64 x45 = (w & 1) ? a5 : a4;
    u64 x67 = (w & 1) ? a7 : a6;
    u64 y0 = (w & 2) ? x23 : x01;
    u64 y1 = (w & 2) ? x67 : x45;
    return (w & 4) ? y1 : y0;
}

// sorted-desc top-8 insertion chain
#define INS8(X, A0, A1, A2, A3, A4, A5, A6, A7) do {                          \
    u64 _x = (X), _n;                                                         \
    _n = fm(A0, _x); _x = fmn(A0, _x); A0 = _n;                               \
    _n = fm(A1, _x); _x = fmn(A1, _x); A1 = _n;                               \
    _n = fm(A2, _x); _x = fmn(A2, _x); A2 = _n;                               \
    _n = fm(A3, _x); _x = fmn(A3, _x); A3 = _n;                               \
    _n = fm(A4, _x); _x = fmn(A4, _x); A4 = _n;                               \
    _n = fm(A5, _x); _x = fmn(A5, _x); A5 = _n;                               \
    _n = fm(A6, _x); _x = fmn(A6, _x); A6 = _n;                               \
    A7 = fm(A7, _x);                                                          \
} while (0)

// ---------------------------------------------------------------------------
// Kernel 1: per-ROW top-T (desc val, asc col) -> out[b] bytes [0, 32K).
// Entry: val_bits<<32 | col.   (proven)
// ---------------------------------------------------------------------------
__global__ __launch_bounds__(256) void build_top(const float* __restrict__ s,
                                                 float* __restrict__ out) {
    const int wave = threadIdx.x >> 6;
    const int lane = threadIdx.x & 63;
    const int row_g = blockIdx.x * 4 + wave;
    const int b = row_g >> 9;
    const int r = row_g & (NN - 1);
    const float* rp = s + (size_t)row_g * NN;
    u64* dst = (u64*)(out + (size_t)b * NN * NN) + (size_t)r * T;

    const float4 a  = *(const float4*)(rp + 4 * lane);
    const float4 c2 = *(const float4*)(rp + 256 + 4 * lane);

    u64 kk0 = (((u64)__float_as_uint(a.x)  + 1) << 9) | (u32)(511 - (4*lane + 0));
    u64 kk1 = (((u64)__float_as_uint(a.y)  + 1) << 9) | (u32)(511 - (4*lane + 1));
    u64 kk2 = (((u64)__float_as_uint(a.z)  + 1) << 9) | (u32)(511 - (4*lane + 2));
    u64 kk3 = (((u64)__float_as_uint(a.w)  + 1) << 9) | (u32)(511 - (4*lane + 3));
    u64 kk4 = (((u64)__float_as_uint(c2.x) + 1) << 9) | (u32)(511 - (256 + 4*lane + 0));
    u64 kk5 = (((u64)__float_as_uint(c2.y) + 1) << 9) | (u32)(511 - (256 + 4*lane + 1));
    u64 kk6 = (((u64)__float_as_uint(c2.z) + 1) << 9) | (u32)(511 - (256 + 4*lane + 2));
    u64 kk7 = (((u64)__float_as_uint(c2.w) + 1) << 9) | (u32)(511 - (256 + 4*lane + 3));

    #pragma unroll
    for (int t = 0; t < T; ++t) {
        u64 m0 = fm(kk0, kk1), m1 = fm(kk2, kk3);
        u64 m2 = fm(kk4, kk5), m3 = fm(kk6, kk7);
        m0 = fm(m0, m1); m2 = fm(m2, m3);
        u64 bk = fm(m0, m2);
        WAVE_FMAX64(bk);
        bk = readlane64(bk, 63);

        const int wcol = 511 - (int)(bk & 511);
        const u32 vb = (u32)(bk >> 9) - 1u;
        if (lane == 0) dst[t] = ((u64)vb << 32) | (u32)wcol;

        const int owner = (wcol & 255) >> 2;
        const int slot  = ((wcol >> 8) << 2) | (wcol & 3);
        if (lane == owner) {
            kk0 = (slot == 0) ? 0 : kk0;  kk1 = (slot == 1) ? 0 : kk1;
            kk2 = (slot == 2) ? 0 : kk2;  kk3 = (slot == 3) ? 0 : kk3;
            kk4 = (slot == 4) ? 0 : kk4;  kk5 = (slot == 5) ? 0 : kk5;
            kk6 = (slot == 6) ? 0 : kk6;  kk7 = (slot == 7) ? 0 : kk7;
        }
    }
}

// ---------------------------------------------------------------------------
// Kernel 1b: per-COL top-T (desc val, asc row) -> out[b] bytes [32K, 64K).
// Entry: ((val_bits+1)<<9) | (511-row).   (proven round 12)
// ---------------------------------------------------------------------------
__global__ __launch_bounds__(256) void build_col(const float* __restrict__ s,
                                                 float* __restrict__ out) {
    const int b = blockIdx.x >> 3;
    const int cbase = (blockIdx.x & 7) * 64;
    const int t = threadIdx.x;
    const int ct = t & 63, q = t >> 6;

    __shared__ float tile[64][65];
    __shared__ u64 mrg[64][4][8];

    const float* sb = s + (size_t)b * NN * NN;

    u64 t0 = 0, t1 = 0, t2 = 0, t3 = 0, t4 = 0, t5 = 0, t6 = 0, t7 = 0;

    for (int ch = 0; ch < 8; ++ch) {
        const int rbase = ch * 64;
        #pragma unroll
        for (int i = 0; i < 16; ++i) {
            const int rl_ = q + 4 * i;
            tile[rl_][ct] = sb[(size_t)(rbase + rl_) * NN + cbase + ct];
        }
        __syncthreads();
        #pragma unroll
        for (int i = 0; i < 16; ++i) {
            const int rr = rbase + q * 16 + i;
            const float v = tile[q * 16 + i][ct];
            const u64 x = (((u64)__float_as_uint(v) + 1) << 9) | (u32)(511 - rr);
            INS8(x, t0, t1, t2, t3, t4, t5, t6, t7);
        }
        __syncthreads();
    }

    mrg[ct][q][0] = t0;  mrg[ct][q][1] = t1;  mrg[ct][q][2] = t2;
    mrg[ct][q][3] = t3;  mrg[ct][q][4] = t4;  mrg[ct][q][5] = t5;
    mrg[ct][q][6] = t6;  mrg[ct][q][7] = t7;
    __syncthreads();

    if (t < 64) {
        u64 m0 = 0, m1 = 0, m2 = 0, m3 = 0, m4 = 0, m5 = 0, m6 = 0, m7 = 0;
        #pragma unroll
        for (int qq = 0; qq < 4; ++qq)
            #pragma unroll
            for (int ii = 0; ii < 8; ++ii) {
                const u64 x = mrg[t][qq][ii];
                INS8(x, m0, m1, m2, m3, m4, m5, m6, m7);
            }
        u64* dst = (u64*)(out + (size_t)b * NN * NN) + (size_t)NN * T
                 + (size_t)(cbase + t) * T;
        dst[0] = m0; dst[1] = m1; dst[2] = m2; dst[3] = m3;
        dst[4] = m4; dst[5] = m5; dst[6] = m6; dst[7] = m7;
    }
}

// ---------------------------------------------------------------------------
// Kernel 2: HYBRID. Phase A: exact parallel handshake (alive > ATH), fully
// parallel commits, register alive masks, batched repairs, slot-7 cold
// persistence. Phase B: round-6 lazy sequential on the remainder. All
// output writes deferred to one parallel pass from match16[].
// key = (val_bits+1)<<32 | (512-row)<<16 | col ; DEADK = row dead.
// ---------------------------------------------------------------------------
__global__ __launch_bounds__(64) void greedy_hs(const float* __restrict__ s,
                                                float* __restrict__ out) {
    __shared__ __align__(16) u64 rl[NN][9];    // 36 KB (padded stride 72B)
    __shared__ __align__(16) u64 cl[NN][9];    // 36 KB
    __shared__ u32 colh[NN];                   // 2 KB
    __shared__ u8 aliveR[NN];
    __shared__ u8 aliveC[NN];
    __shared__ u16 match16[NN];                // 1 KB

    const int b = blockIdx.x;
    const int lane = threadIdx.x;
    const float* sb = s + (size_t)b * NN * NN;
    float* ob = out + (size_t)b * NN * NN;

    // ---- stage lists into padded LDS ----
    {
        const ulonglong2* src = (const ulonglong2*)ob;
        #pragma unroll
        for (int i = 0; i < 32; ++i) {
            const int i2 = lane + 64 * i;
            const ulonglong2 vR = src[i2];
            const ulonglong2 vC = src[2048 + i2];
            const int idx = i2 * 2;
            rl[idx >> 3][idx & 7] = vR.x;  rl[idx >> 3][(idx & 7) + 1] = vR.y;
            cl[idx >> 3][idx & 7] = vC.x;  cl[idx >> 3][(idx & 7) + 1] = vC.y;
        }
    }
    ((u32*)aliveR)[lane] = 0x01010101u;  ((u32*)aliveR)[64 + lane] = 0x01010101u;
    ((u32*)aliveC)[lane] = 0x01010101u;  ((u32*)aliveC)[64 + lane] = 0x01010101u;

    u64 k0, k1, k2, k3, k4, k5, k6, k7;
    u32 ch0, ch1, ch2, ch3, ch4, ch5, ch6, ch7;
#define INITJ(j, KJ, CHJ) do {                                                \
        const int r_ = lane + 64 * (j);                                       \
        const u64 e_ = rl[r_][0];                                             \
        KJ = (((e_ >> 32) + 1ull) << 32)                                      \
           | ((u64)(u32)(512 - r_) << 16) | (e_ & 511ull);                    \
        const u64 g_ = cl[r_][0];                                             \
        CHJ = 511u - ((u32)g_ & 511u);                                        \
        colh[r_] = CHJ;                                                       \
    } while (0)
    INITJ(0, k0, ch0); INITJ(1, k1, ch1); INITJ(2, k2, ch2); INITJ(3, k3, ch3);
    INITJ(4, k4, ch4); INITJ(5, k5, ch5); INITJ(6, k6, ch6); INITJ(7, k7, ch7);
#undef INITJ

    u64 am0 = ~0ull, am1 = ~0ull, am2 = ~0ull, am3 = ~0ull,
        am4 = ~0ull, am5 = ~0ull, am6 = ~0ull, am7 = ~0ull;   // alive cols
    u64 ar0 = ~0ull, ar1 = ~0ull, ar2 = ~0ull, ar3 = ~0ull,
        ar4 = ~0ull, ar5 = ~0ull, ar6 = ~0ull, ar7 = ~0ull;   // alive rows

#define ALIVE_C(cc) ((amsel((int)(cc) >> 6, am0,am1,am2,am3,am4,am5,am6,am7)  \
                      >> ((cc) & 63)) & 1ull)
#define ALIVE_R(rr) ((amsel((int)(rr) >> 6, ar0,ar1,ar2,ar3,ar4,ar5,ar6,ar7)  \
                      >> ((rr) & 63)) & 1ull)

#define SETK(RS, VAL) do {                                                    \
        const int rsl_ = (RS) & 63, rsj_ = (RS) >> 6;                         \
        const bool mn_ = (lane == rsl_);                                      \
        k0 = (mn_ && rsj_ == 0) ? (VAL) : k0;                                 \
        k1 = (mn_ && rsj_ == 1) ? (VAL) : k1;                                 \
        k2 = (mn_ && rsj_ == 2) ? (VAL) : k2;                                 \
        k3 = (mn_ && rsj_ == 3) ? (VAL) : k3;                                 \
        k4 = (mn_ && rsj_ == 4) ? (VAL) : k4;                                 \
        k5 = (mn_ && rsj_ == 5) ? (VAL) : k5;                                 \
        k6 = (mn_ && rsj_ == 6) ? (VAL) : k6;                                 \
        k7 = (mn_ && rsj_ == 7) ? (VAL) : k7;                                 \
    } while (0)

// cooperative row reload over alive cols (am masks); persists into rl[][7]
#define COLDROW(RR, NKVAR) do {                                               \
        const float* rp_ = sb + (size_t)(RR) * NN;                            \
        const float4 fa_ = *(const float4*)(rp_ + 4 * lane);                  \
        const float4 fv_ = *(const float4*)(rp_ + 256 + 4 * lane);            \
        const int sh_ = (4 * lane) & 63; const int wq_ = lane >> 4;           \
        u64 xlo_ = (wq_ == 0) ? am0 : (wq_ == 1) ? am1 : (wq_ == 2) ? am2 : am3; \
        u64 xhi_ = (wq_ == 0) ? am4 : (wq_ == 1) ? am5 : (wq_ == 2) ? am6 : am7; \
        const u32 al8_ = ((u32)(xlo_ >> sh_) & 0xFu)                          \
                       | (((u32)(xhi_ >> sh_) & 0xFu) << 4);                  \
        u64 e0_ = (al8_ & 1u)   ? ((((u64)__float_as_uint(fa_.x) + 1) << 9) | (u32)(511 - (4*lane+0))) : 0; \
        u64 e1_ = (al8_ & 2u)   ? ((((u64)__float_as_uint(fa_.y) + 1) << 9) | (u32)(511 - (4*lane+1))) : 0; \
        u64 e2_ = (al8_ & 4u)   ? ((((u64)__float_as_uint(fa_.z) + 1) << 9) | (u32)(511 - (4*lane+2))) : 0; \
        u64 e3_ = (al8_ & 8u)   ? ((((u64)__float_as_uint(fa_.w) + 1) << 9) | (u32)(511 - (4*lane+3))) : 0; \
        u64 e4_ = (al8_ & 16u)  ? ((((u64)__float_as_uint(fv_.x) + 1) << 9) | (u32)(511 - (256+4*lane+0))) : 0; \
        u64 e5_ = (al8_ & 32u)  ? ((((u64)__float_as_uint(fv_.y) + 1) << 9) | (u32)(511 - (256+4*lane+1))) : 0; \
        u64 e6_ = (al8_ & 64u)  ? ((((u64)__float_as_uint(fv_.z) + 1) << 9) | (u32)(511 - (256+4*lane+2))) : 0; \
        u64 e7_ = (al8_ & 128u) ? ((((u64)__float_as_uint(fv_.w) + 1) << 9) | (u32)(511 - (256+4*lane+3))) : 0; \
        u64 n0_ = fm(e0_, e1_), n1_ = fm(e2_, e3_);                           \
        u64 n2_ = fm(e4_, e5_), n3_ = fm(e6_, e7_);                           \
        n0_ = fm(n0_, n1_); n2_ = fm(n2_, n3_);                               \
        u64 bw_ = fm(n0_, n2_);                                               \
        WAVE_FMAX64(bw_);                                                     \
        bw_ = readlane64(bw_, 63);                                            \
        const int wc_ = 511 - (int)(bw_ & 511);                               \
        NKVAR = ((bw_ >> 9) << 32)                                            \
              | ((u64)(u32)(512 - (RR)) << 16) | (u32)wc_;                    \
        if (lane == 0)                                                        \
            rl[RR][7] = (((bw_ >> 9) - 1ull) << 32) | (u32)wc_;               \
    } while (0)

    int alive = NN;

    // ================= PHASE A: handshake =================
    #pragma unroll 1
    for (int round = 0; round < 40; ++round) {
        // P1: detect (row head c with colh[c] == r)
        u32 st = 0;
        u32 cc0, cc1, cc2, cc3, cc4, cc5, cc6, cc7;
#define DET(j, KJ, CCJ) do {                                                  \
        CCJ = (u32)KJ & 511u;                                                 \
        const bool hit_ = (KJ >= LIVEMIN) &&                                  \
                          (colh[CCJ] == (u32)(lane + 64 * (j)));              \
        st |= hit_ ? (1u << (j)) : 0u;                                        \
    } while (0)
        DET(0, k0, cc0); DET(1, k1, cc1); DET(2, k2, cc2); DET(3, k3, cc3);
        DET(4, k4, cc4); DET(5, k5, cc5); DET(6, k6, cc6); DET(7, k7, cc7);
#undef DET
        int cnt = 0;
        #pragma unroll
        for (int j = 0; j < 8; ++j)
            cnt += (int)__builtin_popcountll(__ballot((st >> j) & 1u));
        if (cnt == 0) break;

        // P2: parallel commit
#define CMT(j, KJ, CCJ) do {                                                  \
        if ((st >> (j)) & 1u) {                                               \
            const int r_ = lane + 64 * (j);                                   \
            match16[r_] = (u16)CCJ;                                           \
            aliveC[CCJ] = 0;                                                  \
            aliveR[r_] = 0;                                                   \
            KJ = DEADK;                                                       \
        }                                                                     \
    } while (0)
        CMT(0, k0, cc0); CMT(1, k1, cc1); CMT(2, k2, cc2); CMT(3, k3, cc3);
        CMT(4, k4, cc4); CMT(5, k5, cc5); CMT(6, k6, cc6); CMT(7, k7, cc7);
#undef CMT
        alive -= cnt;

        // rebuild register alive masks from LDS bytes (16 ballots)
        am0 = __ballot(aliveC[lane] != 0);        am1 = __ballot(aliveC[64 + lane] != 0);
        am2 = __ballot(aliveC[128 + lane] != 0);  am3 = __ballot(aliveC[192 + lane] != 0);
        am4 = __ballot(aliveC[256 + lane] != 0);  am5 = __ballot(aliveC[320 + lane] != 0);
        am6 = __ballot(aliveC[384 + lane] != 0);  am7 = __ballot(aliveC[448 + lane] != 0);
        ar0 = __ballot(aliveR[lane] != 0);        ar1 = __ballot(aliveR[64 + lane] != 0);
        ar2 = __ballot(aliveR[128 + lane] != 0);  ar3 = __ballot(aliveR[192 + lane] != 0);
        ar4 = __ballot(aliveR[256 + lane] != 0);  ar5 = __ballot(aliveR[320 + lane] != 0);
        ar6 = __ballot(aliveR[384 + lane] != 0);  ar7 = __ballot(aliveR[448 + lane] != 0);

        if (alive <= ATH) break;   // phase B tolerates stale heads

        // P3: repair row heads (batched, register cascades)
        u32 coldR = 0;
#define REPR(j, KJ) do {                                                      \
        if (KJ >= LIVEMIN && !ALIVE_C((u32)KJ & 511u)) {                      \
            const int r_ = lane + 64 * (j);                                   \
            const u64 f0 = rl[r_][0], f1 = rl[r_][1], f2 = rl[r_][2];         \
            const u64 f3 = rl[r_][3], f4 = rl[r_][4], f5 = rl[r_][5];         \
            const u64 f6 = rl[r_][6], f7 = rl[r_][7];                         \
            const u64 a0_ = ALIVE_C((u32)f0 & 511u);                          \
            const u64 a1_ = ALIVE_C((u32)f1 & 511u);                          \
            const u64 a2_ = ALIVE_C((u32)f2 & 511u);                          \
            const u64 a3_ = ALIVE_C((u32)f3 & 511u);                          \
            const u64 a4_ = ALIVE_C((u32)f4 & 511u);                          \
            const u64 a5_ = ALIVE_C((u32)f5 & 511u);                          \
            const u64 a6_ = ALIVE_C((u32)f6 & 511u);                          \
            const u64 a7_ = ALIVE_C((u32)f7 & 511u);                          \
            u64 sel = 0;                                                      \
            sel = a7_ ? f7 : sel; sel = a6_ ? f6 : sel;                       \
            sel = a5_ ? f5 : sel; sel = a4_ ? f4 : sel;                       \
            sel = a3_ ? f3 : sel; sel = a2_ ? f2 : sel;                       \
            sel = a1_ ? f1 : sel; sel = a0_ ? f0 : sel;                       \
            if (a0_ | a1_ | a2_ | a3_ | a4_ | a5_ | a6_ | a7_) {              \
                KJ = ((sel >> 32) + 1ull) << 32                               \
                   | ((u64)(u32)(512 - r_) << 16) | (sel & 511ull);           \
            } else coldR |= 1u << (j);                                        \
        }                                                                     \
    } while (0)
        REPR(0, k0); REPR(1, k1); REPR(2, k2); REPR(3, k3);
        REPR(4, k4); REPR(5, k5); REPR(6, k6); REPR(7, k7);
#undef REPR
        u64 mk = __ballot(coldR != 0u);
        while (mk) {
            const int l = (int)__builtin_ctzll(mk); mk &= mk - 1;
            u32 lm = (u32)__builtin_amdgcn_readlane((int)coldR, l);
            while (lm) {
                const int jj = (int)__builtin_ctz(lm); lm &= lm - 1;
                const int r = l + 64 * jj;
                u64 nkc;
                COLDROW(r, nkc);
                SETK(r, nkc);
            }
        }

        // P4: repair col heads
        u32 coldC = 0;
#define REPC(j, CHJ, AMJ) do {                                                \
        const int c_ = lane + 64 * (j);                                       \
        if (((AMJ >> lane) & 1ull) && !ALIVE_R(CHJ)) {                        \
            const u64 g0 = cl[c_][0], g1 = cl[c_][1], g2 = cl[c_][2];         \
            const u64 g3 = cl[c_][3], g4 = cl[c_][4], g5 = cl[c_][5];         \
            const u64 g6 = cl[c_][6], g7 = cl[c_][7];                         \
            const u64 b0_ = ALIVE_R(511u - ((u32)g0 & 511u));                 \
            const u64 b1_ = ALIVE_R(511u - ((u32)g1 & 511u));                 \
            const u64 b2_ = ALIVE_R(511u - ((u32)g2 & 511u));                 \
            const u64 b3_ = ALIVE_R(511u - ((u32)g3 & 511u));                 \
            const u64 b4_ = ALIVE_R(511u - ((u32)g4 & 511u));                 \
            const u64 b5_ = ALIVE_R(511u - ((u32)g5 & 511u));                 \
            const u64 b6_ = ALIVE_R(511u - ((u32)g6 & 511u));                 \
            const u64 b7_ = ALIVE_R(511u - ((u32)g7 & 511u));                 \
            u64 sel = 0;                                                      \
            sel = b7_ ? g7 : sel; sel = b6_ ? g6 : sel;                       \
            sel = b5_ ? g5 : sel; sel = b4_ ? g4 : sel;                       \
            sel = b3_ ? g3 : sel; sel = b2_ ? g2 : sel;                       \
            sel = b1_ ? g1 : sel; sel = b0_ ? g0 : sel;                       \
            if (b0_ | b1_ | b2_ | b3_ | b4_ | b5_ | b6_ | b7_) {              \
                CHJ = 511u - ((u32)sel & 511u);                               \
                colh[c_] = CHJ;                                               \
            } else coldC |= 1u << (j);                                        \
        }                                                                     \
    } while (0)
        REPC(0, ch0, am0); REPC(1, ch1, am1); REPC(2, ch2, am2); REPC(3, ch3, am3);
        REPC(4, ch4, am4); REPC(5, ch5, am5); REPC(6, ch6, am6); REPC(7, ch7, am7);
#undef REPC
        mk = __ballot(coldC != 0u);
        while (mk) {
            const int l = (int)__builtin_ctzll(mk); mk &= mk - 1;
            u32 lm = (u32)__builtin_amdgcn_readlane((int)coldC, l);
            while (lm) {
                const int jj = (int)__builtin_ctz(lm); lm &= lm - 1;
                const int c = l + 64 * jj;
                u64 e0 = 0, e1 = 0, e2 = 0, e3 = 0, e4 = 0, e5 = 0, e6 = 0, e7 = 0;
#define CGET(i, EI, ARI) do {                                                 \
                const int rr_ = lane + 64 * (i);                              \
                const float v_ = sb[(size_t)rr_ * NN + c];                    \
                EI = ((ARI >> lane) & 1ull)                                   \
                   ? ((((u64)__float_as_uint(v_) + 1) << 9) | (u32)(511 - rr_))\
                   : 0;                                                       \
            } while (0)
                CGET(0, e0, ar0); CGET(1, e1, ar1); CGET(2, e2, ar2); CGET(3, e3, ar3);
                CGET(4, e4, ar4); CGET(5, e5, ar5); CGET(6, e6, ar6); CGET(7, e7, ar7);
#undef CGET
                u64 n0 = fm(e0, e1), n1 = fm(e2, e3);
                u64 n2 = fm(e4, e5), n3 = fm(e6, e7);
                n0 = fm(n0, n1); n2 = fm(n2, n3);
                u64 bw = fm(n0, n2);
                WAVE_FMAX64(bw);
                bw = readlane64(bw, 63);
                const u32 nr = 511u - ((u32)bw & 511u);
                if (lane == 0) { cl[c][7] = bw; colh[c] = nr; }
                const bool mine = (lane == l);
                ch0 = (mine && jj == 0) ? nr : ch0;  ch1 = (mine && jj == 1) ? nr : ch1;
                ch2 = (mine && jj == 2) ? nr : ch2;  ch3 = (mine && jj == 3) ? nr : ch3;
                ch4 = (mine && jj == 4) ? nr : ch4;  ch5 = (mine && jj == 5) ? nr : ch5;
                ch6 = (mine && jj == 6) ? nr : ch6;  ch7 = (mine && jj == 7) ? nr : ch7;
            }
        }
    }

    // ================= PHASE B: lazy sequential (round-6) =================
    int done = NN - alive;
    #pragma unroll 1
    while (done < NN) {
        u64 m0 = fm(k0, k1), m1 = fm(k2, k3), m2 = fm(k4, k5), m3 = fm(k6, k7);
        m0 = fm(m0, m1); m2 = fm(m2, m3);
        u64 bk = fm(m0, m2);
        WAVE_FMAX64(bk);
        const u32 lo = (u32)__builtin_amdgcn_readlane((int)(u32)bk, 63);
        const int cstar = (int)(lo & 511u);
        const int rstar = 512 - (int)((lo >> 16) & 1023u);

        const u64 e = rl[rstar][lane & 7];
        const int cw = cstar >> 6;
        const u64 aw = amsel(cw, am0, am1, am2, am3, am4, am5, am6, am7);
        const bool valid = ((aw >> (cstar & 63)) & 1ull) != 0ull;

        u64 nk;
        if (valid) {
            if (lane == 0) match16[rstar] = (u16)cstar;
            const u64 nb = ~(1ull << (cstar & 63));
            am0 = (cw == 0) ? (am0 & nb) : am0;  am1 = (cw == 1) ? (am1 & nb) : am1;
            am2 = (cw == 2) ? (am2 & nb) : am2;  am3 = (cw == 3) ? (am3 & nb) : am3;
            am4 = (cw == 4) ? (am4 & nb) : am4;  am5 = (cw == 5) ? (am5 & nb) : am5;
            am6 = (cw == 6) ? (am6 & nb) : am6;  am7 = (cw == 7) ? (am7 & nb) : am7;
            nk = DEADK;
            ++done;
        } else {
            const int c = (int)(e & 511u);
            const u64 w = amsel(c >> 6, am0, am1, am2, am3, am4, am5, am6, am7);
            const bool al = ((w >> (c & 63)) & 1ull) != 0ull;
            const u64 mask = __ballot(al) & 0xFFull;
            if (mask) {
                const u64 es = readlane64(e, (int)__builtin_ctzll(mask));
                nk = (((es >> 32) + 1ull) << 32)
                   | ((u64)(u32)(512 - rstar) << 16) | (es & 511ull);
            } else {
                COLDROW(rstar, nk);
            }
        }
        SETK(rstar, nk);
    }

    // ================= Final parallel output pass =================
    #pragma unroll 4
    for (int rr = 0; rr < NN; ++rr) {
        const int c = (int)match16[rr];
        float4 o0, o1;
        o0.x = (4 * lane + 0 == c) ? 1.0f : 0.0f;
        o0.y = (4 * lane + 1 == c) ? 1.0f : 0.0f;
        o0.z = (4 * lane + 2 == c) ? 1.0f : 0.0f;
        o0.w = (4 * lane + 3 == c) ? 1.0f : 0.0f;
        o1.x = (256 + 4 * lane + 0 == c) ? 1.0f : 0.0f;
        o1.y = (256 + 4 * lane + 1 == c) ? 1.0f : 0.0f;
        o1.z = (256 + 4 * lane + 2 == c) ? 1.0f : 0.0f;
        o1.w = (256 + 4 * lane + 3 == c) ? 1.0f : 0.0f;
        float* orow = ob + ((size_t)rr << 9);
        *(float4*)(orow + 4 * lane) = o0;
        *(float4*)(orow + 256 + 4 * lane) = o1;
    }
}

extern "C" void kernel_launch(void* const* d_in, const int* in_sizes, int n_in,
                              void* d_out, int out_size, void* d_ws, size_t ws_size,
                              hipStream_t stream) {
    const float* s = (const float*)d_in[0];
    float* out = (float*)d_out;

    build_top<<<dim3(BATCH * NN / 4), dim3(256), 0, stream>>>(s, out);
    build_col<<<dim3(BATCH * 8), dim3(256), 0, stream>>>(s, out);
    greedy_hs<<<dim3(BATCH), dim3(64), 0, stream>>>(s, out);
}

// Round 15
// 377.255 us; speedup vs baseline: 1.5438x; 1.2845x over previous
//
#include <hip/hip_runtime.h>

#define NN 512
#define BATCH 256
#define T 8
#define ATH 24

typedef unsigned long long u64;
typedef unsigned u32;
typedef unsigned char u8;
typedef unsigned short u16;

#define DEADK 512ull
#define LIVEMIN (1ull << 32)
#define UNKNOWN 0xFFFFu

__device__ __forceinline__ u64 fm(u64 a, u64 b) {
    return (u64)__double_as_longlong(fmax(__longlong_as_double((long long)a),
                                          __longlong_as_double((long long)b)));
}
__device__ __forceinline__ u64 fmn(u64 a, u64 b) {
    return (u64)__double_as_longlong(fmin(__longlong_as_double((long long)a),
                                          __longlong_as_double((long long)b)));
}

#define DPP_FMAX64(k, ctrl) do {                                              \
    int _lo = (int)(u32)(k); int _hi = (int)((k) >> 32);                      \
    int _olo = __builtin_amdgcn_update_dpp(_lo, _lo, ctrl, 0xf, 0xf, false);  \
    int _ohi = __builtin_amdgcn_update_dpp(_hi, _hi, ctrl, 0xf, 0xf, false);  \
    u64 _o = ((u64)(u32)_ohi << 32) | (u32)_olo;                              \
    (k) = fm((k), _o);                                                        \
} while (0)

#define WAVE_FMAX64(k) do {                                                   \
    DPP_FMAX64(k, 0x111); DPP_FMAX64(k, 0x112); DPP_FMAX64(k, 0x114);         \
    DPP_FMAX64(k, 0x118); DPP_FMAX64(k, 0x142); DPP_FMAX64(k, 0x143);         \
} while (0)

__device__ __forceinline__ u64 readlane64(u64 k, int l) {
    u32 lo = (u32)__builtin_amdgcn_readlane((int)(u32)k, l);
    u32 hi = (u32)__builtin_amdgcn_readlane((int)(k >> 32), l);
    return ((u64)hi << 32) | lo;
}

__device__ __forceinline__ u64 amsel(int w, u64 a0, u64 a1, u64 a2, u64 a3,
                                     u64 a4, u64 a5, u64 a6, u64 a7) {
    u64 x01 = (w & 1) ? a1 : a0;
    u64 x23 = (w & 1) ? a3 : a2;
    u64 x45 = (w & 1) ? a5 : a4;
    u64 x67 = (w & 1) ? a7 : a6;
    u64 y0 = (w & 2) ? x23 : x01;
    u64 y1 = (w & 2) ? x67 : x45;
    return (w & 4) ? y1 : y0;
}

#define INS8(X, A0, A1, A2, A3, A4, A5, A6, A7) do {                          \
    u64 _x = (X), _n;                                                         \
    _n = fm(A0, _x); _x = fmn(A0, _x); A0 = _n;                               \
    _n = fm(A1, _x); _x = fmn(A1, _x); A1 = _n;                               \
    _n = fm(A2, _x); _x = fmn(A2, _x); A2 = _n;                               \
    _n = fm(A3, _x); _x = fmn(A3, _x); A3 = _n;                               \
    _n = fm(A4, _x); _x = fmn(A4, _x); A4 = _n;                               \
    _n = fm(A5, _x); _x = fmn(A5, _x); A5 = _n;                               \
    _n = fm(A6, _x); _x = fmn(A6, _x); A6 = _n;                               \
    A7 = fm(A7, _x);                                                          \
} while (0)

#define ALIVE_C(cc) ((amsel((int)(cc) >> 6, am0,am1,am2,am3,am4,am5,am6,am7)  \
                      >> ((cc) & 63)) & 1ull)
#define ALIVE_R(rr) ((amsel((int)(rr) >> 6, ar0,ar1,ar2,ar3,ar4,ar5,ar6,ar7)  \
                      >> ((rr) & 63)) & 1ull)
#define SETK(RS, VAL) do {                                                    \
        const int rsl_ = (RS) & 63, rsj_ = (RS) >> 6;                         \
        const bool mn_ = (lane == rsl_);                                      \
        k0 = (mn_ && rsj_ == 0) ? (VAL) : k0;                                 \
        k1 = (mn_ && rsj_ == 1) ? (VAL) : k1;                                 \
        k2 = (mn_ && rsj_ == 2) ? (VAL) : k2;                                 \
        k3 = (mn_ && rsj_ == 3) ? (VAL) : k3;                                 \
        k4 = (mn_ && rsj_ == 4) ? (VAL) : k4;                                 \
        k5 = (mn_ && rsj_ == 5) ? (VAL) : k5;                                 \
        k6 = (mn_ && rsj_ == 6) ? (VAL) : k6;                                 \
        k7 = (mn_ && rsj_ == 7) ? (VAL) : k7;                                 \
    } while (0)
#define COLDROW(RR, NKVAR) do {                                               \
        const float* rp_ = sb + (size_t)(RR) * NN;                            \
        const float4 fa_ = *(const float4*)(rp_ + 4 * lane);                  \
        const float4 fv_ = *(const float4*)(rp_ + 256 + 4 * lane);            \
        const int sh_ = (4 * lane) & 63; const int wq_ = lane >> 4;           \
        u64 xlo_ = (wq_ == 0) ? am0 : (wq_ == 1) ? am1 : (wq_ == 2) ? am2 : am3; \
        u64 xhi_ = (wq_ == 0) ? am4 : (wq_ == 1) ? am5 : (wq_ == 2) ? am6 : am7; \
        const u32 al8_ = ((u32)(xlo_ >> sh_) & 0xFu)                          \
                       | (((u32)(xhi_ >> sh_) & 0xFu) << 4);                  \
        u64 e0_ = (al8_ & 1u)   ? ((((u64)__float_as_uint(fa_.x) + 1) << 9) | (u32)(511 - (4*lane+0))) : 0; \
        u64 e1_ = (al8_ & 2u)   ? ((((u64)__float_as_uint(fa_.y) + 1) << 9) | (u32)(511 - (4*lane+1))) : 0; \
        u64 e2_ = (al8_ & 4u)   ? ((((u64)__float_as_uint(fa_.z) + 1) << 9) | (u32)(511 - (4*lane+2))) : 0; \
        u64 e3_ = (al8_ & 8u)   ? ((((u64)__float_as_uint(fa_.w) + 1) << 9) | (u32)(511 - (4*lane+3))) : 0; \
        u64 e4_ = (al8_ & 16u)  ? ((((u64)__float_as_uint(fv_.x) + 1) << 9) | (u32)(511 - (256+4*lane+0))) : 0; \
        u64 e5_ = (al8_ & 32u)  ? ((((u64)__float_as_uint(fv_.y) + 1) << 9) | (u32)(511 - (256+4*lane+1))) : 0; \
        u64 e6_ = (al8_ & 64u)  ? ((((u64)__float_as_uint(fv_.z) + 1) << 9) | (u32)(511 - (256+4*lane+2))) : 0; \
        u64 e7_ = (al8_ & 128u) ? ((((u64)__float_as_uint(fv_.w) + 1) << 9) | (u32)(511 - (256+4*lane+3))) : 0; \
        u64 n0_ = fm(e0_, e1_), n1_ = fm(e2_, e3_);                           \
        u64 n2_ = fm(e4_, e5_), n3_ = fm(e6_, e7_);                           \
        n0_ = fm(n0_, n1_); n2_ = fm(n2_, n3_);                               \
        u64 bw_ = fm(n0_, n2_);                                               \
        WAVE_FMAX64(bw_);                                                     \
        bw_ = readlane64(bw_, 63);                                            \
        const int wc_ = 511 - (int)(bw_ & 511);                               \
        NKVAR = ((bw_ >> 9) << 32)                                            \
              | ((u64)(u32)(512 - (RR)) << 16) | (u32)wc_;                    \
        if (lane == 0)                                                        \
            rl[RR][7] = (((bw_ >> 9) - 1ull) << 32) | (u32)wc_;               \
    } while (0)

// ---------------------------------------------------------------------------
// Kernel 1: per-ROW top-T -> out[b] bytes [0, 32K).  Entry: val<<32|col.
// ---------------------------------------------------------------------------
__global__ __launch_bounds__(256) void build_top(const float* __restrict__ s,
                                                 float* __restrict__ out) {
    const int wave = threadIdx.x >> 6;
    const int lane = threadIdx.x & 63;
    const int row_g = blockIdx.x * 4 + wave;
    const int b = row_g >> 9;
    const int r = row_g & (NN - 1);
    const float* rp = s + (size_t)row_g * NN;
    u64* dst = (u64*)(out + (size_t)b * NN * NN) + (size_t)r * T;

    const float4 a  = *(const float4*)(rp + 4 * lane);
    const float4 c2 = *(const float4*)(rp + 256 + 4 * lane);

    u64 kk0 = (((u64)__float_as_uint(a.x)  + 1) << 9) | (u32)(511 - (4*lane + 0));
    u64 kk1 = (((u64)__float_as_uint(a.y)  + 1) << 9) | (u32)(511 - (4*lane + 1));
    u64 kk2 = (((u64)__float_as_uint(a.z)  + 1) << 9) | (u32)(511 - (4*lane + 2));
    u64 kk3 = (((u64)__float_as_uint(a.w)  + 1) << 9) | (u32)(511 - (4*lane + 3));
    u64 kk4 = (((u64)__float_as_uint(c2.x) + 1) << 9) | (u32)(511 - (256 + 4*lane + 0));
    u64 kk5 = (((u64)__float_as_uint(c2.y) + 1) << 9) | (u32)(511 - (256 + 4*lane + 1));
    u64 kk6 = (((u64)__float_as_uint(c2.z) + 1) << 9) | (u32)(511 - (256 + 4*lane + 2));
    u64 kk7 = (((u64)__float_as_uint(c2.w) + 1) << 9) | (u32)(511 - (256 + 4*lane + 3));

    #pragma unroll
    for (int t = 0; t < T; ++t) {
        u64 m0 = fm(kk0, kk1), m1 = fm(kk2, kk3);
        u64 m2 = fm(kk4, kk5), m3 = fm(kk6, kk7);
        m0 = fm(m0, m1); m2 = fm(m2, m3);
        u64 bk = fm(m0, m2);
        WAVE_FMAX64(bk);
        bk = readlane64(bk, 63);

        const int wcol = 511 - (int)(bk & 511);
        const u32 vb = (u32)(bk >> 9) - 1u;
        if (lane == 0) dst[t] = ((u64)vb << 32) | (u32)wcol;

        const int owner = (wcol & 255) >> 2;
        const int slot  = ((wcol >> 8) << 2) | (wcol & 3);
        if (lane == owner) {
            kk0 = (slot == 0) ? 0 : kk0;  kk1 = (slot == 1) ? 0 : kk1;
            kk2 = (slot == 2) ? 0 : kk2;  kk3 = (slot == 3) ? 0 : kk3;
            kk4 = (slot == 4) ? 0 : kk4;  kk5 = (slot == 5) ? 0 : kk5;
            kk6 = (slot == 6) ? 0 : kk6;  kk7 = (slot == 7) ? 0 : kk7;
        }
    }
}

// ---------------------------------------------------------------------------
// Kernel 1b: per-COL top-T -> out[b] bytes [32K, 64K).
// Entry: ((val+1)<<9) | (511-row).
// ---------------------------------------------------------------------------
__global__ __launch_bounds__(256) void build_col(const float* __restrict__ s,
                                                 float* __restrict__ out) {
    const int b = blockIdx.x >> 3;
    const int cbase = (blockIdx.x & 7) * 64;
    const int t = threadIdx.x;
    const int ct = t & 63, q = t >> 6;

    __shared__ float tile[64][65];
    __shared__ u64 mrg[64][4][8];

    const float* sb = s + (size_t)b * NN * NN;

    u64 t0 = 0, t1 = 0, t2 = 0, t3 = 0, t4 = 0, t5 = 0, t6 = 0, t7 = 0;

    for (int ch = 0; ch < 8; ++ch) {
        const int rbase = ch * 64;
        #pragma unroll
        for (int i = 0; i < 16; ++i) {
            const int rr = q + 4 * i;
            tile[rr][ct] = sb[(size_t)(rbase + rr) * NN + cbase + ct];
        }
        __syncthreads();
        #pragma unroll
        for (int i = 0; i < 16; ++i) {
            const int rr = rbase + q * 16 + i;
            const float v = tile[q * 16 + i][ct];
            const u64 x = (((u64)__float_as_uint(v) + 1) << 9) | (u32)(511 - rr);
            INS8(x, t0, t1, t2, t3, t4, t5, t6, t7);
        }
        __syncthreads();
    }

    mrg[ct][q][0] = t0;  mrg[ct][q][1] = t1;  mrg[ct][q][2] = t2;
    mrg[ct][q][3] = t3;  mrg[ct][q][4] = t4;  mrg[ct][q][5] = t5;
    mrg[ct][q][6] = t6;  mrg[ct][q][7] = t7;
    __syncthreads();

    if (t < 64) {
        u64 m0 = 0, m1 = 0, m2 = 0, m3 = 0, m4 = 0, m5 = 0, m6 = 0, m7 = 0;
        #pragma unroll
        for (int qq = 0; qq < 4; ++qq)
            #pragma unroll
            for (int ii = 0; ii < 8; ++ii) {
                const u64 x = mrg[t][qq][ii];
                INS8(x, m0, m1, m2, m3, m4, m5, m6, m7);
            }
        u64* dst = (u64*)(out + (size_t)b * NN * NN) + (size_t)NN * T
                 + (size_t)(cbase + t) * T;
        dst[0] = m0; dst[1] = m1; dst[2] = m2; dst[3] = m3;
        dst[4] = m4; dst[5] = m5; dst[6] = m6; dst[7] = m7;
    }
}

// ---------------------------------------------------------------------------
// Kernel 2a: handshake phase (exact parallel commits). State handoff:
// keys -> out slab u64[8192..8704), amc -> u64[8704..8712),
// match16 -> ws_mat (stride 256 u32 per batch).
// ---------------------------------------------------------------------------
__global__ __launch_bounds__(64) void greedy_A(const float* __restrict__ s,
                                               float* __restrict__ out,
                                               u32* __restrict__ ws_mat) {
    __shared__ __align__(16) u64 rl[NN][9];
    __shared__ __align__(16) u64 cl[NN][9];
    __shared__ u32 colh[NN];
    __shared__ u8 aliveR[NN];
    __shared__ u8 aliveC[NN];
    __shared__ u16 match16[NN];

    const int b = blockIdx.x;
    const int lane = threadIdx.x;
    const float* sb = s + (size_t)b * NN * NN;
    float* ob = out + (size_t)b * NN * NN;
    u64* st = (u64*)ob + 8192;           // keys at [64K), amc at [64K+4K)

    {
        const ulonglong2* src = (const ulonglong2*)ob;
        #pragma unroll
        for (int i = 0; i < 32; ++i) {
            const int i2 = lane + 64 * i;
            const ulonglong2 vR = src[i2];
            const ulonglong2 vC = src[2048 + i2];
            const int idx = i2 * 2;
            rl[idx >> 3][idx & 7] = vR.x;  rl[idx >> 3][(idx & 7) + 1] = vR.y;
            cl[idx >> 3][idx & 7] = vC.x;  cl[idx >> 3][(idx & 7) + 1] = vC.y;
        }
    }
    ((u32*)aliveR)[lane] = 0x01010101u;  ((u32*)aliveR)[64 + lane] = 0x01010101u;
    ((u32*)aliveC)[lane] = 0x01010101u;  ((u32*)aliveC)[64 + lane] = 0x01010101u;
    // init match16 (deterministic; B overwrites unmatched rows later)
    match16[lane] = 0; match16[64 + lane] = 0;
    match16[128 + lane] = 0; match16[192 + lane] = 0;
    match16[256 + lane] = 0; match16[320 + lane] = 0;
    match16[384 + lane] = 0; match16[448 + lane] = 0;

    u64 k0, k1, k2, k3, k4, k5, k6, k7;
    u32 ch0, ch1, ch2, ch3, ch4, ch5, ch6, ch7;
#define INITJ(j, KJ, CHJ) do {                                                \
        const int r_ = lane + 64 * (j);                                       \
        const u64 e_ = rl[r_][0];                                             \
        KJ = (((e_ >> 32) + 1ull) << 32)                                      \
           | ((u64)(u32)(512 - r_) << 16) | (e_ & 511ull);                    \
        const u64 g_ = cl[r_][0];                                             \
        CHJ = 511u - ((u32)g_ & 511u);                                        \
        colh[r_] = CHJ;                                                       \
    } while (0)
    INITJ(0, k0, ch0); INITJ(1, k1, ch1); INITJ(2, k2, ch2); INITJ(3, k3, ch3);
    INITJ(4, k4, ch4); INITJ(5, k5, ch5); INITJ(6, k6, ch6); INITJ(7, k7, ch7);
#undef INITJ

    u64 am0 = ~0ull, am1 = ~0ull, am2 = ~0ull, am3 = ~0ull,
        am4 = ~0ull, am5 = ~0ull, am6 = ~0ull, am7 = ~0ull;
    u64 ar0 = ~0ull, ar1 = ~0ull, ar2 = ~0ull, ar3 = ~0ull,
        ar4 = ~0ull, ar5 = ~0ull, ar6 = ~0ull, ar7 = ~0ull;

    int alive = NN;

    #pragma unroll 1
    for (int round = 0; round < 64; ++round) {
        u32 st8 = 0;
        u32 cc0, cc1, cc2, cc3, cc4, cc5, cc6, cc7;
#define DET(j, KJ, CCJ) do {                                                  \
        CCJ = (u32)KJ & 511u;                                                 \
        const bool hit_ = (KJ >= LIVEMIN) &&                                  \
                          (colh[CCJ] == (u32)(lane + 64 * (j)));              \
        st8 |= hit_ ? (1u << (j)) : 0u;                                       \
    } while (0)
        DET(0, k0, cc0); DET(1, k1, cc1); DET(2, k2, cc2); DET(3, k3, cc3);
        DET(4, k4, cc4); DET(5, k5, cc5); DET(6, k6, cc6); DET(7, k7, cc7);
#undef DET
        int cnt = 0;
        #pragma unroll
        for (int j = 0; j < 8; ++j)
            cnt += (int)__builtin_popcountll(__ballot((st8 >> j) & 1u));
        if (cnt == 0) break;

#define CMT(j, KJ, CCJ) do {                                                  \
        if ((st8 >> (j)) & 1u) {                                              \
            const int r_ = lane + 64 * (j);                                   \
            match16[r_] = (u16)CCJ;                                           \
            aliveC[CCJ] = 0;                                                  \
            aliveR[r_] = 0;                                                   \
            KJ = DEADK;                                                       \
        }                                                                     \
    } while (0)
        CMT(0, k0, cc0); CMT(1, k1, cc1); CMT(2, k2, cc2); CMT(3, k3, cc3);
        CMT(4, k4, cc4); CMT(5, k5, cc5); CMT(6, k6, cc6); CMT(7, k7, cc7);
#undef CMT
        alive -= cnt;

        am0 = __ballot(aliveC[lane] != 0);        am1 = __ballot(aliveC[64 + lane] != 0);
        am2 = __ballot(aliveC[128 + lane] != 0);  am3 = __ballot(aliveC[192 + lane] != 0);
        am4 = __ballot(aliveC[256 + lane] != 0);  am5 = __ballot(aliveC[320 + lane] != 0);
        am6 = __ballot(aliveC[384 + lane] != 0);  am7 = __ballot(aliveC[448 + lane] != 0);
        ar0 = __ballot(aliveR[lane] != 0);        ar1 = __ballot(aliveR[64 + lane] != 0);
        ar2 = __ballot(aliveR[128 + lane] != 0);  ar3 = __ballot(aliveR[192 + lane] != 0);
        ar4 = __ballot(aliveR[256 + lane] != 0);  ar5 = __ballot(aliveR[320 + lane] != 0);
        ar6 = __ballot(aliveR[384 + lane] != 0);  ar7 = __ballot(aliveR[448 + lane] != 0);

        if (alive <= ATH) break;

        u32 coldR = 0;
#define REPR(j, KJ) do {                                                      \
        if (KJ >= LIVEMIN && !ALIVE_C((u32)KJ & 511u)) {                      \
            const int r_ = lane + 64 * (j);                                   \
            const u64 f0 = rl[r_][0], f1 = rl[r_][1], f2 = rl[r_][2];         \
            const u64 f3 = rl[r_][3], f4 = rl[r_][4], f5 = rl[r_][5];         \
            const u64 f6 = rl[r_][6], f7 = rl[r_][7];                         \
            const u64 a0_ = ALIVE_C((u32)f0 & 511u);                          \
            const u64 a1_ = ALIVE_C((u32)f1 & 511u);                          \
            const u64 a2_ = ALIVE_C((u32)f2 & 511u);                          \
            const u64 a3_ = ALIVE_C((u32)f3 & 511u);                          \
            const u64 a4_ = ALIVE_C((u32)f4 & 511u);                          \
            const u64 a5_ = ALIVE_C((u32)f5 & 511u);                          \
            const u64 a6_ = ALIVE_C((u32)f6 & 511u);                          \
            const u64 a7_ = ALIVE_C((u32)f7 & 511u);                          \
            u64 sel = 0;                                                      \
            sel = a7_ ? f7 : sel; sel = a6_ ? f6 : sel;                       \
            sel = a5_ ? f5 : sel; sel = a4_ ? f4 : sel;                       \
            sel = a3_ ? f3 : sel; sel = a2_ ? f2 : sel;                       \
            sel = a1_ ? f1 : sel; sel = a0_ ? f0 : sel;                       \
            if (a0_ | a1_ | a2_ | a3_ | a4_ | a5_ | a6_ | a7_) {              \
                KJ = ((sel >> 32) + 1ull) << 32                               \
                   | ((u64)(u32)(512 - r_) << 16) | (sel & 511ull);           \
            } else coldR |= 1u << (j);                                        \
        }                                                                     \
    } while (0)
        REPR(0, k0); REPR(1, k1); REPR(2, k2); REPR(3, k3);
        REPR(4, k4); REPR(5, k5); REPR(6, k6); REPR(7, k7);
#undef REPR
        u64 mk = __ballot(coldR != 0u);
        while (mk) {
            const int l = (int)__builtin_ctzll(mk); mk &= mk - 1;
            u32 lm = (u32)__builtin_amdgcn_readlane((int)coldR, l);
            while (lm) {
                const int jj = (int)__builtin_ctz(lm); lm &= lm - 1;
                const int r = l + 64 * jj;
                u64 nkc;
                COLDROW(r, nkc);
                SETK(r, nkc);
            }
        }

#define REPC(j, CHJ, AMJ) do {                                                \
        const int c_ = lane + 64 * (j);                                       \
        if (((AMJ >> lane) & 1ull) && CHJ != UNKNOWN && !ALIVE_R(CHJ)) {      \
            const u64 g0 = cl[c_][0], g1 = cl[c_][1], g2 = cl[c_][2];         \
            const u64 g3 = cl[c_][3], g4 = cl[c_][4], g5 = cl[c_][5];         \
            const u64 g6 = cl[c_][6], g7 = cl[c_][7];                         \
            const u64 b0_ = ALIVE_R(511u - ((u32)g0 & 511u));                 \
            const u64 b1_ = ALIVE_R(511u - ((u32)g1 & 511u));                 \
            const u64 b2_ = ALIVE_R(511u - ((u32)g2 & 511u));                 \
            const u64 b3_ = ALIVE_R(511u - ((u32)g3 & 511u));                 \
            const u64 b4_ = ALIVE_R(511u - ((u32)g4 & 511u));                 \
            const u64 b5_ = ALIVE_R(511u - ((u32)g5 & 511u));                 \
            const u64 b6_ = ALIVE_R(511u - ((u32)g6 & 511u));                 \
            const u64 b7_ = ALIVE_R(511u - ((u32)g7 & 511u));                 \
            u64 sel = 0;                                                      \
            sel = b7_ ? g7 : sel; sel = b6_ ? g6 : sel;                       \
            sel = b5_ ? g5 : sel; sel = b4_ ? g4 : sel;                       \
            sel = b3_ ? g3 : sel; sel = b2_ ? g2 : sel;                       \
            sel = b1_ ? g1 : sel; sel = b0_ ? g0 : sel;                       \
            if (b0_ | b1_ | b2_ | b3_ | b4_ | b5_ | b6_ | b7_) {              \
                CHJ = 511u - ((u32)sel & 511u);                               \
            } else {                                                          \
                CHJ = UNKNOWN;                                                \
            }                                                                 \
            colh[c_] = CHJ;                                                   \
        }                                                                     \
    } while (0)
        REPC(0, ch0, am0); REPC(1, ch1, am1); REPC(2, ch2, am2); REPC(3, ch3, am3);
        REPC(4, ch4, am4); REPC(5, ch5, am5); REPC(6, ch6, am6); REPC(7, ch7, am7);
#undef REPC
    }

    // ---- dump state: keys+amc to out slab, match16 to ws_mat (stride 256) ----
    st[lane]       = k0;  st[lane + 64]  = k1;
    st[lane + 128] = k2;  st[lane + 192] = k3;
    st[lane + 256] = k4;  st[lane + 320] = k5;
    st[lane + 384] = k6;  st[lane + 448] = k7;
    if (lane < 8)
        st[512 + lane] = amsel(lane, am0, am1, am2, am3, am4, am5, am6, am7);
    const u32* m32 = (const u32*)match16;
    #pragma unroll
    for (int i = 0; i < 4; ++i)
        ws_mat[b * 256 + lane + 64 * i] = m32[lane + 64 * i];
}

// ---------------------------------------------------------------------------
// Kernel 2b: lazy endgame (round-6 proven loop) on the remainder.
// ---------------------------------------------------------------------------
__global__ __launch_bounds__(64) void greedy_B(const float* __restrict__ s,
                                               const float* __restrict__ out,
                                               u32* __restrict__ ws_mat) {
    __shared__ __align__(16) u64 rl[NN][8];
    __shared__ u16 match16[NN];

    const int b = blockIdx.x;
    const int lane = threadIdx.x;
    const float* sb = s + (size_t)b * NN * NN;
    const float* ob = out + (size_t)b * NN * NN;
    const u64* st = (const u64*)ob + 8192;

    {
        const ulonglong2* src = (const ulonglong2*)ob;
        ulonglong2* dstl = (ulonglong2*)&rl[0][0];
        #pragma unroll
        for (int j = 0; j < 32; ++j)
            dstl[lane + 64 * j] = src[lane + 64 * j];
    }
    {
        u32* m32 = (u32*)match16;
        #pragma unroll
        for (int i = 0; i < 4; ++i)
            m32[lane + 64 * i] = ws_mat[b * 256 + lane + 64 * i];
    }

    u64 am0 = st[512], am1 = st[513], am2 = st[514], am3 = st[515];
    u64 am4 = st[516], am5 = st[517], am6 = st[518], am7 = st[519];

    u64 k0 = st[lane];        u64 k1 = st[lane + 64];
    u64 k2 = st[lane + 128];  u64 k3 = st[lane + 192];
    u64 k4 = st[lane + 256];  u64 k5 = st[lane + 320];
    u64 k6 = st[lane + 384];  u64 k7 = st[lane + 448];

    int done = NN;
    done -= (int)__builtin_popcountll(__ballot(k0 >= LIVEMIN));
    done -= (int)__builtin_popcountll(__ballot(k1 >= LIVEMIN));
    done -= (int)__builtin_popcountll(__ballot(k2 >= LIVEMIN));
    done -= (int)__builtin_popcountll(__ballot(k3 >= LIVEMIN));
    done -= (int)__builtin_popcountll(__ballot(k4 >= LIVEMIN));
    done -= (int)__builtin_popcountll(__ballot(k5 >= LIVEMIN));
    done -= (int)__builtin_popcountll(__ballot(k6 >= LIVEMIN));
    done -= (int)__builtin_popcountll(__ballot(k7 >= LIVEMIN));

    #pragma unroll 1
    while (done < NN) {
        u64 m0 = fm(k0, k1), m1 = fm(k2, k3), m2 = fm(k4, k5), m3 = fm(k6, k7);
        m0 = fm(m0, m1); m2 = fm(m2, m3);
        u64 bk = fm(m0, m2);
        WAVE_FMAX64(bk);
        const u32 lo = (u32)__builtin_amdgcn_readlane((int)(u32)bk, 63);
        const int cstar = (int)(lo & 511u);
        const int rstar = 512 - (int)((lo >> 16) & 1023u);

        const u64 e = rl[rstar][lane & 7];
        const int cw = cstar >> 6;
        const u64 aw = amsel(cw, am0, am1, am2, am3, am4, am5, am6, am7);
        const bool valid = ((aw >> (cstar & 63)) & 1ull) != 0ull;

        u64 nk;
        if (valid) {
            if (lane == 0) match16[rstar] = (u16)cstar;
            const u64 nb = ~(1ull << (cstar & 63));
            am0 = (cw == 0) ? (am0 & nb) : am0;  am1 = (cw == 1) ? (am1 & nb) : am1;
            am2 = (cw == 2) ? (am2 & nb) : am2;  am3 = (cw == 3) ? (am3 & nb) : am3;
            am4 = (cw == 4) ? (am4 & nb) : am4;  am5 = (cw == 5) ? (am5 & nb) : am5;
            am6 = (cw == 6) ? (am6 & nb) : am6;  am7 = (cw == 7) ? (am7 & nb) : am7;
            nk = DEADK;
            ++done;
        } else {
            const int c = (int)(e & 511u);
            const u64 w = amsel(c >> 6, am0, am1, am2, am3, am4, am5, am6, am7);
            const bool al = ((w >> (c & 63)) & 1ull) != 0ull;
            const u64 mask = __ballot(al) & 0xFFull;
            if (mask) {
                const u64 es = readlane64(e, (int)__builtin_ctzll(mask));
                nk = (((es >> 32) + 1ull) << 32)
                   | ((u64)(u32)(512 - rstar) << 16) | (es & 511ull);
            } else {
                COLDROW(rstar, nk);
            }
        }
        SETK(rstar, nk);
    }

    {
        const u32* m32 = (const u32*)match16;
        #pragma unroll
        for (int i = 0; i < 4; ++i)
            ws_mat[b * 256 + lane + 64 * i] = m32[lane + 64 * i];
    }
}

// ---------------------------------------------------------------------------
// Kernel 3: fully parallel one-hot output from match16 (stride 256 u32).
// ---------------------------------------------------------------------------
__global__ __launch_bounds__(256) void write_out(const u32* __restrict__ ws_mat,
                                                 float* __restrict__ out) {
    const int gid = blockIdx.x * 256 + threadIdx.x;
    const int b = gid >> 16;
    const int rem = gid & 65535;
    const int row = rem >> 7;
    const int quad = rem & 127;
    const u32 w = ws_mat[b * 256 + (row >> 1)];
    const int c = (int)((w >> (16 * (row & 1))) & 0xFFFFu);
    float4 f;
    f.x = (c == quad * 4 + 0) ? 1.0f : 0.0f;
    f.y = (c == quad * 4 + 1) ? 1.0f : 0.0f;
    f.z = (c == quad * 4 + 2) ? 1.0f : 0.0f;
    f.w = (c == quad * 4 + 3) ? 1.0f : 0.0f;
    ((float4*)out)[gid] = f;
}

extern "C" void kernel_launch(void* const* d_in, const int* in_sizes, int n_in,
                              void* d_out, int out_size, void* d_ws, size_t ws_size,
                              hipStream_t stream) {
    const float* s = (const float*)d_in[0];
    float* out = (float*)d_out;
    u32* ws_mat = (u32*)d_ws;   // BATCH * 256 u32 = 256 KB (well under 1 MB)

    build_top<<<dim3(BATCH * NN / 4), dim3(256), 0, stream>>>(s, out);
    build_col<<<dim3(BATCH * 8), dim3(256), 0, stream>>>(s, out);
    greedy_A<<<dim3(BATCH), dim3(64), 0, stream>>>(s, out, ws_mat);
    greedy_B<<<dim3(BATCH), dim3(64), 0, stream>>>(s, out, ws_mat);
    write_out<<<dim3(BATCH * 256), dim3(256), 0, stream>>>(ws_mat, out);
}